// Round 9
// baseline (271.943 us; speedup 1.0000x reference)
//
#include <hip/hip_runtime.h>
#include <hip/hip_bf16.h>
#include <math.h>

// CapsuleLayer dynamic routing.
// Identity: routing bias after round r = hat · (v0+...+v_{r-1}) — no bias
// buffer; each route pass uses veff = running sum of v.
// Pipeline (4 kernels):
//   k1      : hat = x·W -> bf16 ws (LDS-staged uint4 stores) + round-1 partials
//   squashA : veff1 = squash(sum sPart1 / C); zeroes per-b counters
//   route2  : round 2 -> sPartR1
//   route3  : inline veff2 = veff1 + squash(sum sPartR1); round 3 -> sPartR2;
//             last block per b (atomic counter) reduces+squashes -> out
//
// k1 store lesson (R6/R8 failures + fill-kernel evidence): store BW needs
// 16B/lane stores, not occupancy. Compute in the proven 52-VGPR (c,o2) map,
// stage packed rows in LDS, cooperatively store uint4.

#define B_ 256
#define I_ 1152
#define D_ 8
#define C_ 10
#define O_ 16
#define CO_ (C_*O_)   // 160
#define EPS_ 1e-7f

// k1 geometry (R5/R7-proven compute): 4 ig x 80 (c,o2) = 320 thr; BT=16.
#define IC1 16
#define NIC1 (I_/IC1)   // 72
#define BT 16
#define NBT (B_/BT)     // 16
#define T1 320
// k_route geometry
#define IC3 128
#define NIC3 (I_/IC3)   // 9
#define T3 320          // 32 il x 10 c

// ---------------------------------------------------------------------------
// K1: hat[b,i,c,o] = sum_d x[b,i,d] W[i,c,d,o]  (bf16), plus round-1 partials.
// Per stage k: each ig computes i = i0+ig*4+k for all 16 b's, packs bf16x2
// into LDS; barrier; 1280 uint4 cooperative stores (16B/lane); barrier.
// ---------------------------------------------------------------------------
__global__ __launch_bounds__(T1) void k1_hat(
    const float* __restrict__ x,       // [B,I,D]
    const float* __restrict__ W,       // [I,C,D,O]
    __hip_bfloat16* __restrict__ hat,  // [B,I,CO]
    float* __restrict__ sPart1)        // [NIC1][B][CO]
{
    __shared__ float xs[BT * IC1 * D_];   // 8 KB
    __shared__ float sred[BT][CO_];       // 10 KB
    __shared__ unsigned hst[4 * BT * 80]; // 20 KB  (4 ig x 16 bb x 80 uints)
    const int tid = threadIdx.x;
    const int ic = blockIdx.x, bt = blockIdx.y;
    const int i0 = ic * IC1, b0 = bt * BT;

    // cooperative x tile load, float4 (512; rows are 32B-aligned)
    for (int j = tid; j < BT * IC1 * D_ / 4; j += T1) {
        const int bb = j >> 5, r = j & 31;
        ((float4*)xs)[j] =
            *(const float4*)&x[(((size_t)(b0 + bb)) * I_ + i0) * D_ + r * 4];
    }
    __syncthreads();

    const int ig = tid / 80, r = tid % 80;
    const int c = r / 8, o2 = r % 8;
    const int rowbb = tid / 20, seg = tid % 20;   // for cooperative stores

    float2 acc[BT];
    #pragma unroll
    for (int bb = 0; bb < BT; ++bb) acc[bb] = make_float2(0.0f, 0.0f);

    const float2* W2 = (const float2*)W;

    for (int k = 0; k < 4; ++k) {
        const int i = i0 + ig * 4 + k;
        float2 wv[D_];
        const float2* wp = W2 + ((size_t)i * C_ + c) * (D_ * O_ / 2) + o2;
        #pragma unroll
        for (int d = 0; d < D_; ++d) wv[d] = wp[d * (O_ / 2)];
        #pragma unroll
        for (int bb = 0; bb < BT; ++bb) {
            const float* xp = &xs[(bb * IC1 + ig * 4 + k) * D_];
            float h0 = 0.0f, h1 = 0.0f;
            #pragma unroll
            for (int d = 0; d < D_; ++d) {
                const float xv = xp[d];
                h0 = fmaf(xv, wv[d].x, h0);
                h1 = fmaf(xv, wv[d].y, h1);
            }
            acc[bb].x += h0; acc[bb].y += h1;
            __hip_bfloat162 pk = __float22bfloat162_rn(make_float2(h0, h1));
            hst[(ig * BT + bb) * 80 + c * 8 + o2] = *(unsigned*)&pk;
        }
        __syncthreads();
        // cooperative wide store: iteration t stores ig-group t's i.
        for (int t = 0; t < 4; ++t) {
            const int ii = i0 + t * 4 + k;
            const uint4 v = ((const uint4*)hst)[tid + t * 320];
            ((uint4*)hat)[((size_t)(b0 + rowbb) * I_ + ii) * 20 + seg] = v;
        }
        __syncthreads();   // WAR: hst overwritten next stage
    }

    // staged reduce over the 4 ig groups (deterministic)
    if (ig == 0) {
        #pragma unroll
        for (int bb = 0; bb < BT; ++bb) {
            sred[bb][c * O_ + o2 * 2]     = acc[bb].x;
            sred[bb][c * O_ + o2 * 2 + 1] = acc[bb].y;
        }
    }
    __syncthreads();
    #pragma unroll
    for (int g = 1; g < 4; ++g) {
        if (ig == g) {
            #pragma unroll
            for (int bb = 0; bb < BT; ++bb) {
                sred[bb][c * O_ + o2 * 2]     += acc[bb].x;
                sred[bb][c * O_ + o2 * 2 + 1] += acc[bb].y;
            }
        }
        __syncthreads();
    }
    if (tid < CO_) {
        for (int bb = 0; bb < BT; ++bb)
            sPart1[((size_t)ic * B_ + (b0 + bb)) * CO_ + tid] = sred[bb][tid];
    }
}

// ---------------------------------------------------------------------------
// Shared route body: thread = (il 0..31, c 0..9); vr[] = veff row for c.
// ---------------------------------------------------------------------------
__device__ __forceinline__ void route_body(
    const __hip_bfloat16* __restrict__ hat, const float* vr,
    float* __restrict__ sPartR, int ic, int b, int il, int c, int tid)
{
    __shared__ float pb[32][C_];
    __shared__ float sr[32][CO_ + 4];
    const int i0 = ic * IC3;

    float sacc[O_];
    #pragma unroll
    for (int o = 0; o < O_; ++o) sacc[o] = 0.0f;

    for (int sb = 0; sb < IC3 / 32; ++sb) {   // 4 batches, 1 i per thread
        const int i = i0 + sb * 32 + il;
        const uint4* hp = (const uint4*)&hat[((size_t)b * I_ + i) * CO_ + c * O_];
        const uint4 ha = hp[0], hb = hp[1];
        float hf[O_];
        {
            const unsigned u[8] = {ha.x, ha.y, ha.z, ha.w, hb.x, hb.y, hb.z, hb.w};
            #pragma unroll
            for (int q = 0; q < 8; ++q) {
                hf[2 * q]     = __uint_as_float(u[q] << 16);
                hf[2 * q + 1] = __uint_as_float(u[q] & 0xffff0000u);
            }
        }
        float p = 0.0f;
        #pragma unroll
        for (int o = 0; o < O_; ++o) p = fmaf(hf[o], vr[o], p);
        pb[il][c] = p;
        __syncthreads();
        float pv[C_];
        #pragma unroll
        for (int q = 0; q < C_; ++q) pv[q] = pb[il][q];
        float m = pv[0];
        #pragma unroll
        for (int q = 1; q < C_; ++q) m = fmaxf(m, pv[q]);
        float sum = 0.0f;
        #pragma unroll
        for (int q = 0; q < C_; ++q) sum += __expf(pv[q] - m);
        const float route = __expf(p - m) * __builtin_amdgcn_rcpf(sum);
        #pragma unroll
        for (int o = 0; o < O_; ++o) sacc[o] = fmaf(route, hf[o], sacc[o]);
        __syncthreads();   // WAR: pb overwritten next batch
    }

    #pragma unroll
    for (int o = 0; o < O_; ++o) sr[il][c * O_ + o] = sacc[o];
    __syncthreads();
    if (tid < CO_) {
        float s = 0.0f;
        #pragma unroll
        for (int k = 0; k < 32; ++k) s += sr[k][tid];
        sPartR[((size_t)ic * B_ + b) * CO_ + tid] = s;
    }
}

// Round 2: veff read from buffer.
__global__ __launch_bounds__(T3) void k_route2(
    const __hip_bfloat16* __restrict__ hat,  // [B,I,CO]
    const float* __restrict__ veff,          // [B,CO]
    float* __restrict__ sPartR)              // [NIC3][B][CO]
{
    const int tid = threadIdx.x;
    const int il = tid / C_, c = tid % C_;
    const int ic = blockIdx.x, b = blockIdx.y;
    float vr[O_];
    #pragma unroll
    for (int o = 0; o < O_; ++o) vr[o] = veff[(size_t)b * CO_ + c * O_ + o];
    route_body(hat, vr, sPartR, ic, b, il, c, tid);
}

// ---------------------------------------------------------------------------
// Round 3: inline veff2 = veff1 + squash(sum sPartR1); after writing its
// sPartR2 chunk, the LAST block per b (device-scope atomic counter) reduces
// all 9 chunks in fixed order (deterministic), squashes, writes out.
// ---------------------------------------------------------------------------
__global__ __launch_bounds__(T3) void k_route3(
    const __hip_bfloat16* __restrict__ hat,  // [B,I,CO]
    const float* __restrict__ veff1,         // [B,CO]
    const float* __restrict__ sPartR1,       // [NIC3][B][CO]
    float* __restrict__ sPartR2,             // [NIC3][B][CO]
    int* __restrict__ counter,               // [B]
    float* __restrict__ out)                 // [B,CO]
{
    __shared__ float veffs[CO_];
    __shared__ int lastflag;
    const int tid = threadIdx.x;
    const int il = tid / C_, c = tid % C_;
    const int ic = blockIdx.x, b = blockIdx.y;

    if (tid < CO_) {
        float s = 0.0f;
        #pragma unroll
        for (int k = 0; k < NIC3; ++k)
            s += sPartR1[((size_t)k * B_ + b) * CO_ + tid];
        float n2 = s * s;
        n2 += __shfl_xor(n2, 1);
        n2 += __shfl_xor(n2, 2);
        n2 += __shfl_xor(n2, 4);
        n2 += __shfl_xor(n2, 8);
        const float sc = n2 / ((1.0f + n2) * sqrtf(n2 + EPS_));
        veffs[tid] = veff1[(size_t)b * CO_ + tid] + s * sc;
    }
    __syncthreads();

    float vr[O_];
    #pragma unroll
    for (int o = 0; o < O_; ++o) vr[o] = veffs[c * O_ + o];
    route_body(hat, vr, sPartR2, ic, b, il, c, tid);

    // ---- fused final squash (last block per b) ----
    __syncthreads();                // all sPartR2 writes of this block issued
    if (tid == 0) {
        __threadfence();            // release: make them device-visible
        const int old = atomicAdd(&counter[b], 1);
        lastflag = (old == NIC3 - 1);
    }
    __syncthreads();
    if (lastflag) {
        __threadfence();            // acquire
        if (tid < CO_) {
            const volatile float* vp = (const volatile float*)sPartR2;
            float s = 0.0f;
            #pragma unroll
            for (int k = 0; k < NIC3; ++k)
                s += vp[((size_t)k * B_ + b) * CO_ + tid];
            float n2 = s * s;
            n2 += __shfl_xor(n2, 1);
            n2 += __shfl_xor(n2, 2);
            n2 += __shfl_xor(n2, 4);
            n2 += __shfl_xor(n2, 8);
            const float sc = n2 / ((1.0f + n2) * sqrtf(n2 + EPS_));
            out[(size_t)b * CO_ + tid] = s * sc;
        }
    }
}

// ---------------------------------------------------------------------------
// K_squash: reduce partials (4-way split), squash, dst = v; zero counter[b].
// ---------------------------------------------------------------------------
__global__ __launch_bounds__(640) void k_squash(
    const float* __restrict__ sPart,   // [nchunk][B][CO]
    int nchunk, float scale,
    float* __restrict__ dst,           // [B,CO]
    int* __restrict__ counter)         // [B] or null
{
    __shared__ float red[4][CO_];
    const int b = blockIdx.x, tid = threadIdx.x;
    const int q = tid / CO_;
    const int co = tid % CO_;
    if (counter && tid == 0) counter[b] = 0;
    float s = 0.0f;
    for (int k = q; k < nchunk; k += 4)
        s += sPart[((size_t)k * B_ + b) * CO_ + co];
    red[q][co] = s;
    __syncthreads();
    if (tid < CO_) {
        s = (red[0][co] + red[1][co]) + (red[2][co] + red[3][co]);
        s *= scale;
        float n2 = s * s;
        n2 += __shfl_xor(n2, 1);
        n2 += __shfl_xor(n2, 2);
        n2 += __shfl_xor(n2, 4);
        n2 += __shfl_xor(n2, 8);
        const float sc = n2 / ((1.0f + n2) * sqrtf(n2 + EPS_));
        dst[(size_t)b * CO_ + co] = s * sc;
    }
}

// ---------------------------------------------------------------------------
// Fallback: fully fused single kernel (~402 us) if ws too small
// ---------------------------------------------------------------------------
#define THREADS 640
#define ILG 8
#define SUBI 4
#define CHUNK (ILG*SUBI)
#define NITER (I_/CHUNK)

__global__ __launch_bounds__(THREADS) void capsule_routing_kernel(
    const float* __restrict__ x, const float* __restrict__ W,
    float* __restrict__ out)
{
    __shared__ float bias[I_ * C_];
    __shared__ float spart[ILG][C_ * O_];
    __shared__ float sv[C_ * O_];
    __shared__ float vv[C_ * O_];
    __shared__ float ech[CHUNK][C_];
    __shared__ float scale[C_];

    const int b   = blockIdx.x;
    const int tid = threadIdx.x;
    for (int j = tid; j < I_ * C_; j += THREADS) bias[j] = 0.0f;
    const int il = tid / 80;
    const int rr = tid % 80;
    const int c  = rr / 8;
    const int o2 = rr % 8;
    const int o0 = o2 * 2;
    const float* xb = x + (size_t)b * I_ * D_;
    const float2* W2 = (const float2*)W;
    __syncthreads();
    {
        float acc0 = 0.0f, acc1 = 0.0f;
        for (int it = 0; it < NITER; ++it) {
            #pragma unroll
            for (int sub = 0; sub < SUBI; ++sub) {
                const int i = it * CHUNK + sub * ILG + il;
                const float* xi = xb + i * D_;
                const float2* wp = W2 + (i * C_ + c) * (D_ * O_ / 2) + o2;
                float h0 = 0.0f, h1 = 0.0f;
                #pragma unroll
                for (int d = 0; d < D_; ++d) {
                    float2 w = wp[d * (O_ / 2)];
                    float xv = xi[d];
                    h0 = fmaf(xv, w.x, h0);
                    h1 = fmaf(xv, w.y, h1);
                }
                acc0 += h0; acc1 += h1;
            }
        }
        spart[il][c * O_ + o0]     = acc0;
        spart[il][c * O_ + o0 + 1] = acc1;
    }
    __syncthreads();
    if (tid < C_ * O_) {
        float s = 0.0f;
        #pragma unroll
        for (int k = 0; k < ILG; ++k) s += spart[k][tid];
        sv[tid] = s * (1.0f / C_);
    }
    __syncthreads();
    if (tid < C_) {
        float n2 = 0.0f;
        #pragma unroll
        for (int o = 0; o < O_; ++o) { float t = sv[tid * O_ + o]; n2 = fmaf(t, t, n2); }
        scale[tid] = n2 / ((1.0f + n2) * sqrtf(n2 + EPS_));
    }
    __syncthreads();
    if (tid < C_ * O_) vv[tid] = sv[tid] * scale[tid / O_];
    __syncthreads();
    for (int pass = 1; pass < 3; ++pass) {
        float sa0 = 0.0f, sa1 = 0.0f;
        for (int it = 0; it < NITER; ++it) {
            float h0s[SUBI], h1s[SUBI];
            const float v0 = vv[c * O_ + o0];
            const float v1 = vv[c * O_ + o0 + 1];
            #pragma unroll
            for (int sub = 0; sub < SUBI; ++sub) {
                const int i = it * CHUNK + sub * ILG + il;
                const float* xi = xb + i * D_;
                const float2* wp = W2 + (i * C_ + c) * (D_ * O_ / 2) + o2;
                float h0 = 0.0f, h1 = 0.0f;
                #pragma unroll
                for (int d = 0; d < D_; ++d) {
                    float2 w = wp[d * (O_ / 2)];
                    float xv = xi[d];
                    h0 = fmaf(xv, w.x, h0);
                    h1 = fmaf(xv, w.y, h1);
                }
                h0s[sub] = h0; h1s[sub] = h1;
                float p = h0 * v0 + h1 * v1;
                p += __shfl_xor(p, 1);
                p += __shfl_xor(p, 2);
                p += __shfl_xor(p, 4);
                if (o2 == 0) bias[i * C_ + c] += p;
            }
            __syncthreads();
            if (tid < CHUNK * C_) {
                const int il2 = tid / C_, cc = tid % C_;
                const int i = it * CHUNK + il2;
                float m = -1e30f;
                #pragma unroll
                for (int k = 0; k < C_; ++k) m = fmaxf(m, bias[i * C_ + k]);
                ech[il2][cc] = __expf(bias[i * C_ + cc] - m);
            }
            __syncthreads();
            #pragma unroll
            for (int sub = 0; sub < SUBI; ++sub) {
                const int icx = sub * ILG + il;
                float sum = 0.0f;
                #pragma unroll
                for (int k = 0; k < C_; ++k) sum += ech[icx][k];
                const float route = ech[icx][c] / sum;
                sa0 = fmaf(route, h0s[sub], sa0);
                sa1 = fmaf(route, h1s[sub], sa1);
            }
            __syncthreads();
        }
        spart[il][c * O_ + o0]     = sa0;
        spart[il][c * O_ + o0 + 1] = sa1;
        __syncthreads();
        if (tid < C_ * O_) {
            float s = 0.0f;
            #pragma unroll
            for (int k = 0; k < ILG; ++k) s += spart[k][tid];
            sv[tid] = s;
        }
        __syncthreads();
        if (tid < C_) {
            float n2 = 0.0f;
            #pragma unroll
            for (int o = 0; o < O_; ++o) { float t = sv[tid * O_ + o]; n2 = fmaf(t, t, n2); }
            scale[tid] = n2 / ((1.0f + n2) * sqrtf(n2 + EPS_));
        }
        __syncthreads();
        if (tid < C_ * O_) vv[tid] = sv[tid] * scale[tid / O_];
        __syncthreads();
    }
    if (tid < C_ * O_) out[(size_t)b * C_ * O_ + tid] = vv[tid];
}

// ---------------------------------------------------------------------------
extern "C" void kernel_launch(void* const* d_in, const int* in_sizes, int n_in,
                              void* d_out, int out_size, void* d_ws, size_t ws_size,
                              hipStream_t stream) {
    (void)in_sizes; (void)n_in; (void)out_size;
    const float* x = (const float*)d_in[0];
    const float* W = (const float*)d_in[1];
    float* out = (float*)d_out;

    const size_t hat_b  = (size_t)B_ * I_ * CO_ * sizeof(__hip_bfloat16); // 94.4 MB
    const size_t sp1_b  = (size_t)NIC1 * B_ * CO_ * sizeof(float);        // 11.8 MB
    const size_t spr_b  = (size_t)NIC3 * B_ * CO_ * sizeof(float);        //  1.5 MB
    const size_t v_b    = (size_t)B_ * CO_ * sizeof(float);               //  160 KB
    const size_t cnt_b  = (size_t)B_ * sizeof(int);                       //    1 KB
    const size_t need   = hat_b + sp1_b + 2 * spr_b + v_b + cnt_b;

    if (ws_size >= need) {
        char* p = (char*)d_ws;
        __hip_bfloat16* hat = (__hip_bfloat16*)p;  p += hat_b;
        float* sPart1  = (float*)p;                p += sp1_b;
        float* sPartR1 = (float*)p;                p += spr_b;
        float* sPartR2 = (float*)p;                p += spr_b;
        float* veff1   = (float*)p;                p += v_b;
        int*   counter = (int*)p;

        k1_hat<<<dim3(NIC1, NBT), T1, 0, stream>>>(x, W, hat, sPart1);
        k_squash<<<B_, 640, 0, stream>>>(sPart1, NIC1, 1.0f / C_, veff1, counter);
        k_route2<<<dim3(NIC3, B_), T3, 0, stream>>>(hat, veff1, sPartR1);
        k_route3<<<dim3(NIC3, B_), T3, 0, stream>>>(hat, veff1, sPartR1, sPartR2,
                                                    counter, out);
    } else {
        capsule_routing_kernel<<<B_, THREADS, 0, stream>>>(x, W, out);
    }
}

// Round 10
// 80.126 us; speedup vs baseline: 3.3940x; 3.3940x over previous
//
#include <hip/hip_runtime.h>
#include <hip/hip_bf16.h>
#include <math.h>

// CapsuleLayer dynamic routing.
// Identity: routing bias after round r = hat · (v0+...+v_{r-1}) — no bias
// buffer; each route pass uses veff = running sum of v.
// Pipeline (5 kernels, R7 structure — NO cross-block atomics/fences: a
// device-scope fence forces a per-XCD L2 writeback on MI355X and serialized
// the whole kernel in R9):
//   k1      : hat = x·W -> bf16 ws (LDS-staged uint4 stores) + round-1 partials
//   squashA : veff1 = squash(sum sPart1 / C)
//   route2  : round 2 -> sPartR1
//   route3  : inline veff2 = veff1 + squash(sum sPartR1); round 3 -> sPartR2
//   squashB : out = squash(sum sPartR2)

#define B_ 256
#define I_ 1152
#define D_ 8
#define C_ 10
#define O_ 16
#define CO_ (C_*O_)   // 160
#define EPS_ 1e-7f

// k1 geometry: 4 ig x 80 (c,o2) = 320 thr; BT=16.
#define IC1 16
#define NIC1 (I_/IC1)   // 72
#define BT 16
#define NBT (B_/BT)     // 16
#define T1 320
// k_route geometry
#define IC3 128
#define NIC3 (I_/IC3)   // 9
#define T3 320          // 32 il x 10 c

// ---------------------------------------------------------------------------
// K1: hat[b,i,c,o] = sum_d x[b,i,d] W[i,c,d,o]  (bf16), plus round-1 partials.
// Per stage k: each ig computes i = i0+ig*4+k for all 16 b's, packs bf16x2
// into LDS; barrier; cooperative uint4 stores (16B/lane); barrier.
// ---------------------------------------------------------------------------
__global__ __launch_bounds__(T1) void k1_hat(
    const float* __restrict__ x,       // [B,I,D]
    const float* __restrict__ W,       // [I,C,D,O]
    __hip_bfloat16* __restrict__ hat,  // [B,I,CO]
    float* __restrict__ sPart1)        // [NIC1][B][CO]
{
    __shared__ float xs[BT * IC1 * D_];   // 8 KB
    __shared__ float sred[BT][CO_];       // 10 KB
    __shared__ unsigned hst[4 * BT * 80]; // 20 KB  (4 ig x 16 bb x 80 uints)
    const int tid = threadIdx.x;
    const int ic = blockIdx.x, bt = blockIdx.y;
    const int i0 = ic * IC1, b0 = bt * BT;

    // cooperative x tile load, float4 (512; rows are 32B-aligned)
    for (int j = tid; j < BT * IC1 * D_ / 4; j += T1) {
        const int bb = j >> 5, r = j & 31;
        ((float4*)xs)[j] =
            *(const float4*)&x[(((size_t)(b0 + bb)) * I_ + i0) * D_ + r * 4];
    }
    __syncthreads();

    const int ig = tid / 80, r = tid % 80;
    const int c = r / 8, o2 = r % 8;
    const int rowbb = tid / 20, seg = tid % 20;   // for cooperative stores

    float2 acc[BT];
    #pragma unroll
    for (int bb = 0; bb < BT; ++bb) acc[bb] = make_float2(0.0f, 0.0f);

    const float2* W2 = (const float2*)W;

    for (int k = 0; k < 4; ++k) {
        const int i = i0 + ig * 4 + k;
        float2 wv[D_];
        const float2* wp = W2 + ((size_t)i * C_ + c) * (D_ * O_ / 2) + o2;
        #pragma unroll
        for (int d = 0; d < D_; ++d) wv[d] = wp[d * (O_ / 2)];
        #pragma unroll
        for (int bb = 0; bb < BT; ++bb) {
            const float* xp = &xs[(bb * IC1 + ig * 4 + k) * D_];
            float h0 = 0.0f, h1 = 0.0f;
            #pragma unroll
            for (int d = 0; d < D_; ++d) {
                const float xv = xp[d];
                h0 = fmaf(xv, wv[d].x, h0);
                h1 = fmaf(xv, wv[d].y, h1);
            }
            acc[bb].x += h0; acc[bb].y += h1;
            __hip_bfloat162 pk = __float22bfloat162_rn(make_float2(h0, h1));
            hst[(ig * BT + bb) * 80 + c * 8 + o2] = *(unsigned*)&pk;
        }
        __syncthreads();
        // cooperative wide store: iteration t stores ig-group t's i.
        for (int t = 0; t < 4; ++t) {
            const int ii = i0 + t * 4 + k;
            const uint4 v = ((const uint4*)hst)[tid + t * 320];
            ((uint4*)hat)[((size_t)(b0 + rowbb) * I_ + ii) * 20 + seg] = v;
        }
        __syncthreads();   // WAR: hst overwritten next stage
    }

    // staged reduce over the 4 ig groups (deterministic)
    if (ig == 0) {
        #pragma unroll
        for (int bb = 0; bb < BT; ++bb) {
            sred[bb][c * O_ + o2 * 2]     = acc[bb].x;
            sred[bb][c * O_ + o2 * 2 + 1] = acc[bb].y;
        }
    }
    __syncthreads();
    #pragma unroll
    for (int g = 1; g < 4; ++g) {
        if (ig == g) {
            #pragma unroll
            for (int bb = 0; bb < BT; ++bb) {
                sred[bb][c * O_ + o2 * 2]     += acc[bb].x;
                sred[bb][c * O_ + o2 * 2 + 1] += acc[bb].y;
            }
        }
        __syncthreads();
    }
    if (tid < CO_) {
        for (int bb = 0; bb < BT; ++bb)
            sPart1[((size_t)ic * B_ + (b0 + bb)) * CO_ + tid] = sred[bb][tid];
    }
}

// ---------------------------------------------------------------------------
// Shared route body: thread = (il 0..31, c 0..9); vr[] = veff row for c.
// ---------------------------------------------------------------------------
__device__ __forceinline__ void route_body(
    const __hip_bfloat16* __restrict__ hat, const float* vr,
    float* __restrict__ sPartR, int ic, int b, int il, int c, int tid)
{
    __shared__ float pb[32][C_];
    __shared__ float sr[32][CO_ + 4];
    const int i0 = ic * IC3;

    float sacc[O_];
    #pragma unroll
    for (int o = 0; o < O_; ++o) sacc[o] = 0.0f;

    for (int sb = 0; sb < IC3 / 32; ++sb) {   // 4 batches, 1 i per thread
        const int i = i0 + sb * 32 + il;
        const uint4* hp = (const uint4*)&hat[((size_t)b * I_ + i) * CO_ + c * O_];
        const uint4 ha = hp[0], hb = hp[1];
        float hf[O_];
        {
            const unsigned u[8] = {ha.x, ha.y, ha.z, ha.w, hb.x, hb.y, hb.z, hb.w};
            #pragma unroll
            for (int q = 0; q < 8; ++q) {
                hf[2 * q]     = __uint_as_float(u[q] << 16);
                hf[2 * q + 1] = __uint_as_float(u[q] & 0xffff0000u);
            }
        }
        float p = 0.0f;
        #pragma unroll
        for (int o = 0; o < O_; ++o) p = fmaf(hf[o], vr[o], p);
        pb[il][c] = p;
        __syncthreads();
        float pv[C_];
        #pragma unroll
        for (int q = 0; q < C_; ++q) pv[q] = pb[il][q];
        float m = pv[0];
        #pragma unroll
        for (int q = 1; q < C_; ++q) m = fmaxf(m, pv[q]);
        float sum = 0.0f;
        #pragma unroll
        for (int q = 0; q < C_; ++q) sum += __expf(pv[q] - m);
        const float route = __expf(p - m) * __builtin_amdgcn_rcpf(sum);
        #pragma unroll
        for (int o = 0; o < O_; ++o) sacc[o] = fmaf(route, hf[o], sacc[o]);
        __syncthreads();   // WAR: pb overwritten next batch
    }

    #pragma unroll
    for (int o = 0; o < O_; ++o) sr[il][c * O_ + o] = sacc[o];
    __syncthreads();
    if (tid < CO_) {
        float s = 0.0f;
        #pragma unroll
        for (int k = 0; k < 32; ++k) s += sr[k][tid];
        sPartR[((size_t)ic * B_ + b) * CO_ + tid] = s;
    }
}

// Round 2: veff read directly from buffer.
__global__ __launch_bounds__(T3) void k_route2(
    const __hip_bfloat16* __restrict__ hat,  // [B,I,CO]
    const float* __restrict__ veff,          // [B,CO]
    float* __restrict__ sPartR)              // [NIC3][B][CO]
{
    const int tid = threadIdx.x;
    const int il = tid / C_, c = tid % C_;
    const int ic = blockIdx.x, b = blockIdx.y;
    float vr[O_];
    #pragma unroll
    for (int o = 0; o < O_; ++o) vr[o] = veff[(size_t)b * CO_ + c * O_ + o];
    route_body(hat, vr, sPartR, ic, b, il, c, tid);
}

// Round 3: veff2 = veff1 + squash(sum_k sPartR1[k]) computed inline.
// Fixed summation order, identical in every block -> deterministic.
__global__ __launch_bounds__(T3) void k_route3(
    const __hip_bfloat16* __restrict__ hat,  // [B,I,CO]
    const float* __restrict__ veff1,         // [B,CO]
    const float* __restrict__ sPartR1,       // [NIC3][B][CO]
    float* __restrict__ sPartR2)             // [NIC3][B][CO]
{
    __shared__ float veffs[CO_];
    const int tid = threadIdx.x;
    const int il = tid / C_, c = tid % C_;
    const int ic = blockIdx.x, b = blockIdx.y;

    if (tid < CO_) {
        float s = 0.0f;
        #pragma unroll
        for (int k = 0; k < NIC3; ++k)
            s += sPartR1[((size_t)k * B_ + b) * CO_ + tid];
        float n2 = s * s;
        n2 += __shfl_xor(n2, 1);
        n2 += __shfl_xor(n2, 2);
        n2 += __shfl_xor(n2, 4);
        n2 += __shfl_xor(n2, 8);
        const float sc = n2 / ((1.0f + n2) * sqrtf(n2 + EPS_));
        veffs[tid] = veff1[(size_t)b * CO_ + tid] + s * sc;
    }
    __syncthreads();

    float vr[O_];
    #pragma unroll
    for (int o = 0; o < O_; ++o) vr[o] = veffs[c * O_ + o];
    route_body(hat, vr, sPartR2, ic, b, il, c, tid);
}

// ---------------------------------------------------------------------------
// K_squash: reduce partials (4-way split), squash, dst = (prev?:0) + v.
// ---------------------------------------------------------------------------
__global__ __launch_bounds__(640) void k_squash(
    const float* __restrict__ sPart,   // [nchunk][B][CO]
    int nchunk, float scale,
    const float* __restrict__ prev,    // [B,CO] or null
    float* __restrict__ dst)           // [B,CO]
{
    __shared__ float red[4][CO_];
    const int b = blockIdx.x, tid = threadIdx.x;
    const int q = tid / CO_;           // 0..3
    const int co = tid % CO_;
    float s = 0.0f;
    for (int k = q; k < nchunk; k += 4)
        s += sPart[((size_t)k * B_ + b) * CO_ + co];
    red[q][co] = s;
    __syncthreads();
    if (tid < CO_) {
        s = (red[0][co] + red[1][co]) + (red[2][co] + red[3][co]);
        s *= scale;
        float n2 = s * s;
        n2 += __shfl_xor(n2, 1);
        n2 += __shfl_xor(n2, 2);
        n2 += __shfl_xor(n2, 4);
        n2 += __shfl_xor(n2, 8);
        const float sc = n2 / ((1.0f + n2) * sqrtf(n2 + EPS_));
        const float v = s * sc;
        dst[(size_t)b * CO_ + co] = (prev ? prev[(size_t)b * CO_ + co] : 0.0f) + v;
    }
}

// ---------------------------------------------------------------------------
// Fallback: fully fused single kernel (~402 us) if ws too small
// ---------------------------------------------------------------------------
#define THREADS 640
#define ILG 8
#define SUBI 4
#define CHUNK (ILG*SUBI)
#define NITER (I_/CHUNK)

__global__ __launch_bounds__(THREADS) void capsule_routing_kernel(
    const float* __restrict__ x, const float* __restrict__ W,
    float* __restrict__ out)
{
    __shared__ float bias[I_ * C_];
    __shared__ float spart[ILG][C_ * O_];
    __shared__ float sv[C_ * O_];
    __shared__ float vv[C_ * O_];
    __shared__ float ech[CHUNK][C_];
    __shared__ float scale[C_];

    const int b   = blockIdx.x;
    const int tid = threadIdx.x;
    for (int j = tid; j < I_ * C_; j += THREADS) bias[j] = 0.0f;
    const int il = tid / 80;
    const int rr = tid % 80;
    const int c  = rr / 8;
    const int o2 = rr % 8;
    const int o0 = o2 * 2;
    const float* xb = x + (size_t)b * I_ * D_;
    const float2* W2 = (const float2*)W;
    __syncthreads();
    {
        float acc0 = 0.0f, acc1 = 0.0f;
        for (int it = 0; it < NITER; ++it) {
            #pragma unroll
            for (int sub = 0; sub < SUBI; ++sub) {
                const int i = it * CHUNK + sub * ILG + il;
                const float* xi = xb + i * D_;
                const float2* wp = W2 + (i * C_ + c) * (D_ * O_ / 2) + o2;
                float h0 = 0.0f, h1 = 0.0f;
                #pragma unroll
                for (int d = 0; d < D_; ++d) {
                    float2 w = wp[d * (O_ / 2)];
                    float xv = xi[d];
                    h0 = fmaf(xv, w.x, h0);
                    h1 = fmaf(xv, w.y, h1);
                }
                acc0 += h0; acc1 += h1;
            }
        }
        spart[il][c * O_ + o0]     = acc0;
        spart[il][c * O_ + o0 + 1] = acc1;
    }
    __syncthreads();
    if (tid < C_ * O_) {
        float s = 0.0f;
        #pragma unroll
        for (int k = 0; k < ILG; ++k) s += spart[k][tid];
        sv[tid] = s * (1.0f / C_);
    }
    __syncthreads();
    if (tid < C_) {
        float n2 = 0.0f;
        #pragma unroll
        for (int o = 0; o < O_; ++o) { float t = sv[tid * O_ + o]; n2 = fmaf(t, t, n2); }
        scale[tid] = n2 / ((1.0f + n2) * sqrtf(n2 + EPS_));
    }
    __syncthreads();
    if (tid < C_ * O_) vv[tid] = sv[tid] * scale[tid / O_];
    __syncthreads();
    for (int pass = 1; pass < 3; ++pass) {
        float sa0 = 0.0f, sa1 = 0.0f;
        for (int it = 0; it < NITER; ++it) {
            float h0s[SUBI], h1s[SUBI];
            const float v0 = vv[c * O_ + o0];
            const float v1 = vv[c * O_ + o0 + 1];
            #pragma unroll
            for (int sub = 0; sub < SUBI; ++sub) {
                const int i = it * CHUNK + sub * ILG + il;
                const float* xi = xb + i * D_;
                const float2* wp = W2 + (i * C_ + c) * (D_ * O_ / 2) + o2;
                float h0 = 0.0f, h1 = 0.0f;
                #pragma unroll
                for (int d = 0; d < D_; ++d) {
                    float2 w = wp[d * (O_ / 2)];
                    float xv = xi[d];
                    h0 = fmaf(xv, w.x, h0);
                    h1 = fmaf(xv, w.y, h1);
                }
                h0s[sub] = h0; h1s[sub] = h1;
                float p = h0 * v0 + h1 * v1;
                p += __shfl_xor(p, 1);
                p += __shfl_xor(p, 2);
                p += __shfl_xor(p, 4);
                if (o2 == 0) bias[i * C_ + c] += p;
            }
            __syncthreads();
            if (tid < CHUNK * C_) {
                const int il2 = tid / C_, cc = tid % C_;
                const int i = it * CHUNK + il2;
                float m = -1e30f;
                #pragma unroll
                for (int k = 0; k < C_; ++k) m = fmaxf(m, bias[i * C_ + k]);
                ech[il2][cc] = __expf(bias[i * C_ + cc] - m);
            }
            __syncthreads();
            #pragma unroll
            for (int sub = 0; sub < SUBI; ++sub) {
                const int icx = sub * ILG + il;
                float sum = 0.0f;
                #pragma unroll
                for (int k = 0; k < C_; ++k) sum += ech[icx][k];
                const float route = ech[icx][c] / sum;
                sa0 = fmaf(route, h0s[sub], sa0);
                sa1 = fmaf(route, h1s[sub], sa1);
            }
            __syncthreads();
        }
        spart[il][c * O_ + o0]     = sa0;
        spart[il][c * O_ + o0 + 1] = sa1;
        __syncthreads();
        if (tid < C_ * O_) {
            float s = 0.0f;
            #pragma unroll
            for (int k = 0; k < ILG; ++k) s += spart[k][tid];
            sv[tid] = s;
        }
        __syncthreads();
        if (tid < C_) {
            float n2 = 0.0f;
            #pragma unroll
            for (int o = 0; o < O_; ++o) { float t = sv[tid * O_ + o]; n2 = fmaf(t, t, n2); }
            scale[tid] = n2 / ((1.0f + n2) * sqrtf(n2 + EPS_));
        }
        __syncthreads();
        if (tid < C_ * O_) vv[tid] = sv[tid] * scale[tid / O_];
        __syncthreads();
    }
    if (tid < C_ * O_) out[(size_t)b * C_ * O_ + tid] = vv[tid];
}

// ---------------------------------------------------------------------------
extern "C" void kernel_launch(void* const* d_in, const int* in_sizes, int n_in,
                              void* d_out, int out_size, void* d_ws, size_t ws_size,
                              hipStream_t stream) {
    (void)in_sizes; (void)n_in; (void)out_size;
    const float* x = (const float*)d_in[0];
    const float* W = (const float*)d_in[1];
    float* out = (float*)d_out;

    const size_t hat_b  = (size_t)B_ * I_ * CO_ * sizeof(__hip_bfloat16); // 94.4 MB
    const size_t sp1_b  = (size_t)NIC1 * B_ * CO_ * sizeof(float);        // 11.8 MB
    const size_t spr_b  = (size_t)NIC3 * B_ * CO_ * sizeof(float);        //  1.5 MB
    const size_t v_b    = (size_t)B_ * CO_ * sizeof(float);               //  160 KB
    const size_t need   = hat_b + sp1_b + 2 * spr_b + v_b;                // ~109.4 MB

    if (ws_size >= need) {
        char* p = (char*)d_ws;
        __hip_bfloat16* hat = (__hip_bfloat16*)p;  p += hat_b;
        float* sPart1  = (float*)p;                p += sp1_b;
        float* sPartR1 = (float*)p;                p += spr_b;
        float* sPartR2 = (float*)p;                p += spr_b;
        float* veff1   = (float*)p;

        k1_hat<<<dim3(NIC1, NBT), T1, 0, stream>>>(x, W, hat, sPart1);
        k_squash<<<B_, 640, 0, stream>>>(sPart1, NIC1, 1.0f / C_, nullptr, veff1);
        k_route2<<<dim3(NIC3, B_), T3, 0, stream>>>(hat, veff1, sPartR1);
        k_route3<<<dim3(NIC3, B_), T3, 0, stream>>>(hat, veff1, sPartR1, sPartR2);
        k_squash<<<B_, 640, 0, stream>>>(sPartR2, NIC3, 1.0f, nullptr, out);
    } else {
        capsule_routing_kernel<<<B_, THREADS, 0, stream>>>(x, W, out);
    }
}

// Round 11
// 76.665 us; speedup vs baseline: 3.5471x; 1.0451x over previous
//
#include <hip/hip_runtime.h>
#include <hip/hip_bf16.h>
#include <math.h>

// CapsuleLayer dynamic routing.
// Identity: routing bias after round r = hat · (v0+...+v_{r-1}) — no bias
// buffer; each route pass uses veff = running sum of v.
// Pipeline (5 kernels, NO cross-block atomics/fences — R9 lesson: a device
// fence forces per-XCD L2 writebacks and serializes wide grids):
//   k1      : hat = x·W -> bf16 ws + round-1 partials (direct bf16x2 stores;
//             store-width experiments R6/R8/R10 all neutral -> k1 is
//             LDS-read/VALU-bound; this version vectorizes LDS reads)
//   squashA : veff1 = squash(sum sPart1 / C)
//   route2  : round 2 -> sPartR1
//   route3  : inline veff2 = veff1 + squash(sum sPartR1); round 3 -> sPartR2
//   squashB : out = squash(sum sPartR2)

#define B_ 256
#define I_ 1152
#define D_ 8
#define C_ 10
#define O_ 16
#define CO_ (C_*O_)   // 160
#define EPS_ 1e-7f

// k1 geometry (R5/R7-proven): 4 ig x 80 (c,o2) = 320 thr; BT=16.
#define IC1 16
#define NIC1 (I_/IC1)   // 72
#define BT 16
#define NBT (B_/BT)     // 16
#define T1 320
// k_route geometry
#define IC3 128
#define NIC3 (I_/IC3)   // 9
#define T3 320          // 32 il x 10 c

// ---------------------------------------------------------------------------
// K1: hat[b,i,c,o] = sum_d x[b,i,d] W[i,c,d,o]  (bf16), plus round-1 partials.
// x tile in LDS; per (i,bb) the 8 x-floats are read as 2x ds_read_b128
// (same addr across wave -> broadcast). W fragment in VGPRs; bf16x2 stores.
// ---------------------------------------------------------------------------
__global__ __launch_bounds__(T1) void k1_hat(
    const float* __restrict__ x,       // [B,I,D]
    const float* __restrict__ W,       // [I,C,D,O]
    __hip_bfloat16* __restrict__ hat,  // [B,I,CO]
    float* __restrict__ sPart1)        // [NIC1][B][CO]
{
    __shared__ float xs[BT * IC1 * D_];   // 8 KB
    __shared__ float sred[BT][CO_];       // 10 KB
    const int tid = threadIdx.x;
    const int ic = blockIdx.x, bt = blockIdx.y;
    const int i0 = ic * IC1, b0 = bt * BT;

    // cooperative x tile load, float4 (512; rows are 32B-aligned)
    for (int j = tid; j < BT * IC1 * D_ / 4; j += T1) {
        const int bb = j >> 5, r = j & 31;
        ((float4*)xs)[j] =
            *(const float4*)&x[(((size_t)(b0 + bb)) * I_ + i0) * D_ + r * 4];
    }
    __syncthreads();

    const int ig = tid / 80, r = tid % 80;
    const int c = r / 8, o2 = r % 8;

    float2 acc[BT];
    #pragma unroll
    for (int bb = 0; bb < BT; ++bb) acc[bb] = make_float2(0.0f, 0.0f);

    const float2* W2 = (const float2*)W;

    for (int k = 0; k < IC1 / 4; ++k) {
        const int il = ig * (IC1 / 4) + k;
        const int i = i0 + il;
        float2 wv[D_];
        const float2* wp = W2 + ((size_t)i * C_ + c) * (D_ * O_ / 2) + o2;
        #pragma unroll
        for (int d = 0; d < D_; ++d) wv[d] = wp[d * (O_ / 2)];
        #pragma unroll
        for (int bb = 0; bb < BT; ++bb) {
            const float4* xp4 = (const float4*)&xs[(bb * IC1 + il) * D_];
            const float4 xa = xp4[0];   // ds_read_b128 (broadcast)
            const float4 xb = xp4[1];
            const float xv[D_] = {xa.x, xa.y, xa.z, xa.w, xb.x, xb.y, xb.z, xb.w};
            float h0 = 0.0f, h1 = 0.0f;
            #pragma unroll
            for (int d = 0; d < D_; ++d) {
                h0 = fmaf(xv[d], wv[d].x, h0);
                h1 = fmaf(xv[d], wv[d].y, h1);
            }
            acc[bb].x += h0; acc[bb].y += h1;
            *(__hip_bfloat162*)&hat[((size_t)(b0 + bb) * I_ + i) * CO_ + c * O_ + o2 * 2] =
                __float22bfloat162_rn(make_float2(h0, h1));
        }
    }

    // staged reduce over the 4 ig groups (deterministic)
    if (ig == 0) {
        #pragma unroll
        for (int bb = 0; bb < BT; ++bb) {
            sred[bb][c * O_ + o2 * 2]     = acc[bb].x;
            sred[bb][c * O_ + o2 * 2 + 1] = acc[bb].y;
        }
    }
    __syncthreads();
    #pragma unroll
    for (int g = 1; g < 4; ++g) {
        if (ig == g) {
            #pragma unroll
            for (int bb = 0; bb < BT; ++bb) {
                sred[bb][c * O_ + o2 * 2]     += acc[bb].x;
                sred[bb][c * O_ + o2 * 2 + 1] += acc[bb].y;
            }
        }
        __syncthreads();
    }
    if (tid < CO_) {
        for (int bb = 0; bb < BT; ++bb)
            sPart1[((size_t)ic * B_ + (b0 + bb)) * CO_ + tid] = sred[bb][tid];
    }
}

// ---------------------------------------------------------------------------
// Shared route body: thread = (il 0..31, c 0..9); vr[] = veff row for c.
// ---------------------------------------------------------------------------
__device__ __forceinline__ void route_body(
    const __hip_bfloat16* __restrict__ hat, const float* vr,
    float* __restrict__ sPartR, int ic, int b, int il, int c, int tid)
{
    __shared__ float pb[32][C_];
    __shared__ float sr[32][CO_ + 4];
    const int i0 = ic * IC3;

    float sacc[O_];
    #pragma unroll
    for (int o = 0; o < O_; ++o) sacc[o] = 0.0f;

    for (int sb = 0; sb < IC3 / 32; ++sb) {   // 4 batches, 1 i per thread
        const int i = i0 + sb * 32 + il;
        const uint4* hp = (const uint4*)&hat[((size_t)b * I_ + i) * CO_ + c * O_];
        const uint4 ha = hp[0], hb = hp[1];
        float hf[O_];
        {
            const unsigned u[8] = {ha.x, ha.y, ha.z, ha.w, hb.x, hb.y, hb.z, hb.w};
            #pragma unroll
            for (int q = 0; q < 8; ++q) {
                hf[2 * q]     = __uint_as_float(u[q] << 16);
                hf[2 * q + 1] = __uint_as_float(u[q] & 0xffff0000u);
            }
        }
        float p = 0.0f;
        #pragma unroll
        for (int o = 0; o < O_; ++o) p = fmaf(hf[o], vr[o], p);
        pb[il][c] = p;
        __syncthreads();
        float pv[C_];
        #pragma unroll
        for (int q = 0; q < C_; ++q) pv[q] = pb[il][q];
        float m = pv[0];
        #pragma unroll
        for (int q = 1; q < C_; ++q) m = fmaxf(m, pv[q]);
        float sum = 0.0f;
        #pragma unroll
        for (int q = 0; q < C_; ++q) sum += __expf(pv[q] - m);
        const float route = __expf(p - m) * __builtin_amdgcn_rcpf(sum);
        #pragma unroll
        for (int o = 0; o < O_; ++o) sacc[o] = fmaf(route, hf[o], sacc[o]);
        __syncthreads();   // WAR: pb overwritten next batch
    }

    #pragma unroll
    for (int o = 0; o < O_; ++o) sr[il][c * O_ + o] = sacc[o];
    __syncthreads();
    if (tid < CO_) {
        float s = 0.0f;
        #pragma unroll
        for (int k = 0; k < 32; ++k) s += sr[k][tid];
        sPartR[((size_t)ic * B_ + b) * CO_ + tid] = s;
    }
}

// Round 2: veff read directly from buffer.
__global__ __launch_bounds__(T3) void k_route2(
    const __hip_bfloat16* __restrict__ hat,  // [B,I,CO]
    const float* __restrict__ veff,          // [B,CO]
    float* __restrict__ sPartR)              // [NIC3][B][CO]
{
    const int tid = threadIdx.x;
    const int il = tid / C_, c = tid % C_;
    const int ic = blockIdx.x, b = blockIdx.y;
    float vr[O_];
    #pragma unroll
    for (int o = 0; o < O_; ++o) vr[o] = veff[(size_t)b * CO_ + c * O_ + o];
    route_body(hat, vr, sPartR, ic, b, il, c, tid);
}

// Round 3: veff2 = veff1 + squash(sum_k sPartR1[k]) computed inline.
// Fixed summation order, identical in every block -> deterministic.
__global__ __launch_bounds__(T3) void k_route3(
    const __hip_bfloat16* __restrict__ hat,  // [B,I,CO]
    const float* __restrict__ veff1,         // [B,CO]
    const float* __restrict__ sPartR1,       // [NIC3][B][CO]
    float* __restrict__ sPartR2)             // [NIC3][B][CO]
{
    __shared__ float veffs[CO_];
    const int tid = threadIdx.x;
    const int il = tid / C_, c = tid % C_;
    const int ic = blockIdx.x, b = blockIdx.y;

    if (tid < CO_) {
        float s = 0.0f;
        #pragma unroll
        for (int k = 0; k < NIC3; ++k)
            s += sPartR1[((size_t)k * B_ + b) * CO_ + tid];
        float n2 = s * s;
        n2 += __shfl_xor(n2, 1);
        n2 += __shfl_xor(n2, 2);
        n2 += __shfl_xor(n2, 4);
        n2 += __shfl_xor(n2, 8);
        const float sc = n2 / ((1.0f + n2) * sqrtf(n2 + EPS_));
        veffs[tid] = veff1[(size_t)b * CO_ + tid] + s * sc;
    }
    __syncthreads();

    float vr[O_];
    #pragma unroll
    for (int o = 0; o < O_; ++o) vr[o] = veffs[c * O_ + o];
    route_body(hat, vr, sPartR2, ic, b, il, c, tid);
}

// ---------------------------------------------------------------------------
// K_squash: reduce partials (4-way split), squash, dst = (prev?:0) + v.
// ---------------------------------------------------------------------------
__global__ __launch_bounds__(640) void k_squash(
    const float* __restrict__ sPart,   // [nchunk][B][CO]
    int nchunk, float scale,
    const float* __restrict__ prev,    // [B,CO] or null
    float* __restrict__ dst)           // [B,CO]
{
    __shared__ float red[4][CO_];
    const int b = blockIdx.x, tid = threadIdx.x;
    const int q = tid / CO_;           // 0..3
    const int co = tid % CO_;
    float s = 0.0f;
    for (int k = q; k < nchunk; k += 4)
        s += sPart[((size_t)k * B_ + b) * CO_ + co];
    red[q][co] = s;
    __syncthreads();
    if (tid < CO_) {
        s = (red[0][co] + red[1][co]) + (red[2][co] + red[3][co]);
        s *= scale;
        float n2 = s * s;
        n2 += __shfl_xor(n2, 1);
        n2 += __shfl_xor(n2, 2);
        n2 += __shfl_xor(n2, 4);
        n2 += __shfl_xor(n2, 8);
        const float sc = n2 / ((1.0f + n2) * sqrtf(n2 + EPS_));
        const float v = s * sc;
        dst[(size_t)b * CO_ + co] = (prev ? prev[(size_t)b * CO_ + co] : 0.0f) + v;
    }
}

// ---------------------------------------------------------------------------
// Fallback: fully fused single kernel (~402 us) if ws too small
// ---------------------------------------------------------------------------
#define THREADS 640
#define ILG 8
#define SUBI 4
#define CHUNK (ILG*SUBI)
#define NITER (I_/CHUNK)

__global__ __launch_bounds__(THREADS) void capsule_routing_kernel(
    const float* __restrict__ x, const float* __restrict__ W,
    float* __restrict__ out)
{
    __shared__ float bias[I_ * C_];
    __shared__ float spart[ILG][C_ * O_];
    __shared__ float sv[C_ * O_];
    __shared__ float vv[C_ * O_];
    __shared__ float ech[CHUNK][C_];
    __shared__ float scale[C_];

    const int b   = blockIdx.x;
    const int tid = threadIdx.x;
    for (int j = tid; j < I_ * C_; j += THREADS) bias[j] = 0.0f;
    const int il = tid / 80;
    const int rr = tid % 80;
    const int c  = rr / 8;
    const int o2 = rr % 8;
    const int o0 = o2 * 2;
    const float* xb = x + (size_t)b * I_ * D_;
    const float2* W2 = (const float2*)W;
    __syncthreads();
    {
        float acc0 = 0.0f, acc1 = 0.0f;
        for (int it = 0; it < NITER; ++it) {
            #pragma unroll
            for (int sub = 0; sub < SUBI; ++sub) {
                const int i = it * CHUNK + sub * ILG + il;
                const float* xi = xb + i * D_;
                const float2* wp = W2 + (i * C_ + c) * (D_ * O_ / 2) + o2;
                float h0 = 0.0f, h1 = 0.0f;
                #pragma unroll
                for (int d = 0; d < D_; ++d) {
                    float2 w = wp[d * (O_ / 2)];
                    float xv = xi[d];
                    h0 = fmaf(xv, w.x, h0);
                    h1 = fmaf(xv, w.y, h1);
                }
                acc0 += h0; acc1 += h1;
            }
        }
        spart[il][c * O_ + o0]     = acc0;
        spart[il][c * O_ + o0 + 1] = acc1;
    }
    __syncthreads();
    if (tid < C_ * O_) {
        float s = 0.0f;
        #pragma unroll
        for (int k = 0; k < ILG; ++k) s += spart[k][tid];
        sv[tid] = s * (1.0f / C_);
    }
    __syncthreads();
    if (tid < C_) {
        float n2 = 0.0f;
        #pragma unroll
        for (int o = 0; o < O_; ++o) { float t = sv[tid * O_ + o]; n2 = fmaf(t, t, n2); }
        scale[tid] = n2 / ((1.0f + n2) * sqrtf(n2 + EPS_));
    }
    __syncthreads();
    if (tid < C_ * O_) vv[tid] = sv[tid] * scale[tid / O_];
    __syncthreads();
    for (int pass = 1; pass < 3; ++pass) {
        float sa0 = 0.0f, sa1 = 0.0f;
        for (int it = 0; it < NITER; ++it) {
            float h0s[SUBI], h1s[SUBI];
            const float v0 = vv[c * O_ + o0];
            const float v1 = vv[c * O_ + o0 + 1];
            #pragma unroll
            for (int sub = 0; sub < SUBI; ++sub) {
                const int i = it * CHUNK + sub * ILG + il;
                const float* xi = xb + i * D_;
                const float2* wp = W2 + (i * C_ + c) * (D_ * O_ / 2) + o2;
                float h0 = 0.0f, h1 = 0.0f;
                #pragma unroll
                for (int d = 0; d < D_; ++d) {
                    float2 w = wp[d * (O_ / 2)];
                    float xv = xi[d];
                    h0 = fmaf(xv, w.x, h0);
                    h1 = fmaf(xv, w.y, h1);
                }
                h0s[sub] = h0; h1s[sub] = h1;
                float p = h0 * v0 + h1 * v1;
                p += __shfl_xor(p, 1);
                p += __shfl_xor(p, 2);
                p += __shfl_xor(p, 4);
                if (o2 == 0) bias[i * C_ + c] += p;
            }
            __syncthreads();
            if (tid < CHUNK * C_) {
                const int il2 = tid / C_, cc = tid % C_;
                const int i = it * CHUNK + il2;
                float m = -1e30f;
                #pragma unroll
                for (int k = 0; k < C_; ++k) m = fmaxf(m, bias[i * C_ + k]);
                ech[il2][cc] = __expf(bias[i * C_ + cc] - m);
            }
            __syncthreads();
            #pragma unroll
            for (int sub = 0; sub < SUBI; ++sub) {
                const int icx = sub * ILG + il;
                float sum = 0.0f;
                #pragma unroll
                for (int k = 0; k < C_; ++k) sum += ech[icx][k];
                const float route = ech[icx][c] / sum;
                sa0 = fmaf(route, h0s[sub], sa0);
                sa1 = fmaf(route, h1s[sub], sa1);
            }
            __syncthreads();
        }
        spart[il][c * O_ + o0]     = sa0;
        spart[il][c * O_ + o0 + 1] = sa1;
        __syncthreads();
        if (tid < C_ * O_) {
            float s = 0.0f;
            #pragma unroll
            for (int k = 0; k < ILG; ++k) s += spart[k][tid];
            sv[tid] = s;
        }
        __syncthreads();
        if (tid < C_) {
            float n2 = 0.0f;
            #pragma unroll
            for (int o = 0; o < O_; ++o) { float t = sv[tid * O_ + o]; n2 = fmaf(t, t, n2); }
            scale[tid] = n2 / ((1.0f + n2) * sqrtf(n2 + EPS_));
        }
        __syncthreads();
        if (tid < C_ * O_) vv[tid] = sv[tid] * scale[tid / O_];
        __syncthreads();
    }
    if (tid < C_ * O_) out[(size_t)b * C_ * O_ + tid] = vv[tid];
}

// ---------------------------------------------------------------------------
extern "C" void kernel_launch(void* const* d_in, const int* in_sizes, int n_in,
                              void* d_out, int out_size, void* d_ws, size_t ws_size,
                              hipStream_t stream) {
    (void)in_sizes; (void)n_in; (void)out_size;
    const float* x = (const float*)d_in[0];
    const float* W = (const float*)d_in[1];
    float* out = (float*)d_out;

    const size_t hat_b  = (size_t)B_ * I_ * CO_ * sizeof(__hip_bfloat16); // 94.4 MB
    const size_t sp1_b  = (size_t)NIC1 * B_ * CO_ * sizeof(float);        // 11.8 MB
    const size_t spr_b  = (size_t)NIC3 * B_ * CO_ * sizeof(float);        //  1.5 MB
    const size_t v_b    = (size_t)B_ * CO_ * sizeof(float);               //  160 KB
    const size_t need   = hat_b + sp1_b + 2 * spr_b + v_b;                // ~109.4 MB

    if (ws_size >= need) {
        char* p = (char*)d_ws;
        __hip_bfloat16* hat = (__hip_bfloat16*)p;  p += hat_b;
        float* sPart1  = (float*)p;                p += sp1_b;
        float* sPartR1 = (float*)p;                p += spr_b;
        float* sPartR2 = (float*)p;                p += spr_b;
        float* veff1   = (float*)p;

        k1_hat<<<dim3(NIC1, NBT), T1, 0, stream>>>(x, W, hat, sPart1);
        k_squash<<<B_, 640, 0, stream>>>(sPart1, NIC1, 1.0f / C_, nullptr, veff1);
        k_route2<<<dim3(NIC3, B_), T3, 0, stream>>>(hat, veff1, sPartR1);
        k_route3<<<dim3(NIC3, B_), T3, 0, stream>>>(hat, veff1, sPartR1, sPartR2);
        k_squash<<<B_, 640, 0, stream>>>(sPartR2, NIC3, 1.0f, nullptr, out);
    } else {
        capsule_routing_kernel<<<B_, THREADS, 0, stream>>>(x, W, out);
    }
}

// Round 12
// 61.660 us; speedup vs baseline: 4.4103x; 1.2433x over previous
//
#include <hip/hip_runtime.h>
#include <hip/hip_bf16.h>
#include <math.h>

// CapsuleLayer dynamic routing.
// Identity: routing bias after round r = hat · (v0+...+v_{r-1}) — each route
// round only needs veff = running sum of v, 160 floats per b.
// Pipeline (2 kernels, 1 gap; NO cross-block atomics/fences — R9 lesson):
//   k1        : hat = x·W -> bf16 ws + round-1 partials sPart1
//   route_all : one block per b: veff1 = squash(mean s1) -> round 2 (full I,
//               in-block reduce+squash) -> veff2 -> round 3 -> out.
// k1 lessons (R6/R8/R10/R11): store-width, occupancy and LDS-read experiments
// all neutral — k1 stays in its proven R5/R7 shape.

#define B_ 256
#define I_ 1152
#define D_ 8
#define C_ 10
#define O_ 16
#define CO_ (C_*O_)   // 160
#define EPS_ 1e-7f

// k1 geometry (proven): 4 ig x 80 (c,o2) = 320 thr; BT=16.
#define IC1 16
#define NIC1 (I_/IC1)   // 72
#define BT 16
#define NBT (B_/BT)     // 16
#define T1 320
// route_all geometry: 64 il x 10 c = 640 threads; 18 batches of 64 i.
#define TRA 640
#define NBATCH (I_/64)  // 18

// ---------------------------------------------------------------------------
// K1: hat[b,i,c,o] = sum_d x[b,i,d] W[i,c,d,o]  (bf16), plus round-1 partials.
// ---------------------------------------------------------------------------
__global__ __launch_bounds__(T1) void k1_hat(
    const float* __restrict__ x,       // [B,I,D]
    const float* __restrict__ W,       // [I,C,D,O]
    __hip_bfloat16* __restrict__ hat,  // [B,I,CO]
    float* __restrict__ sPart1)        // [NIC1][B][CO]
{
    __shared__ float xs[BT * IC1 * D_];   // 8 KB
    __shared__ float sred[BT][CO_];       // 10 KB
    const int tid = threadIdx.x;
    const int ic = blockIdx.x, bt = blockIdx.y;
    const int i0 = ic * IC1, b0 = bt * BT;

    // cooperative x tile load, float4 (512; rows are 32B-aligned)
    for (int j = tid; j < BT * IC1 * D_ / 4; j += T1) {
        const int bb = j >> 5, r = j & 31;
        ((float4*)xs)[j] =
            *(const float4*)&x[(((size_t)(b0 + bb)) * I_ + i0) * D_ + r * 4];
    }
    __syncthreads();

    const int ig = tid / 80, r = tid % 80;
    const int c = r / 8, o2 = r % 8;

    float2 acc[BT];
    #pragma unroll
    for (int bb = 0; bb < BT; ++bb) acc[bb] = make_float2(0.0f, 0.0f);

    const float2* W2 = (const float2*)W;

    for (int k = 0; k < IC1 / 4; ++k) {
        const int il = ig * (IC1 / 4) + k;
        const int i = i0 + il;
        float2 wv[D_];
        const float2* wp = W2 + ((size_t)i * C_ + c) * (D_ * O_ / 2) + o2;
        #pragma unroll
        for (int d = 0; d < D_; ++d) wv[d] = wp[d * (O_ / 2)];
        #pragma unroll
        for (int bb = 0; bb < BT; ++bb) {
            const float4* xp4 = (const float4*)&xs[(bb * IC1 + il) * D_];
            const float4 xa = xp4[0];   // ds_read_b128 (broadcast)
            const float4 xb = xp4[1];
            const float xv[D_] = {xa.x, xa.y, xa.z, xa.w, xb.x, xb.y, xb.z, xb.w};
            float h0 = 0.0f, h1 = 0.0f;
            #pragma unroll
            for (int d = 0; d < D_; ++d) {
                h0 = fmaf(xv[d], wv[d].x, h0);
                h1 = fmaf(xv[d], wv[d].y, h1);
            }
            acc[bb].x += h0; acc[bb].y += h1;
            *(__hip_bfloat162*)&hat[((size_t)(b0 + bb) * I_ + i) * CO_ + c * O_ + o2 * 2] =
                __float22bfloat162_rn(make_float2(h0, h1));
        }
    }

    // staged reduce over the 4 ig groups (deterministic)
    if (ig == 0) {
        #pragma unroll
        for (int bb = 0; bb < BT; ++bb) {
            sred[bb][c * O_ + o2 * 2]     = acc[bb].x;
            sred[bb][c * O_ + o2 * 2 + 1] = acc[bb].y;
        }
    }
    __syncthreads();
    #pragma unroll
    for (int g = 1; g < 4; ++g) {
        if (ig == g) {
            #pragma unroll
            for (int bb = 0; bb < BT; ++bb) {
                sred[bb][c * O_ + o2 * 2]     += acc[bb].x;
                sred[bb][c * O_ + o2 * 2 + 1] += acc[bb].y;
            }
        }
        __syncthreads();
    }
    if (tid < CO_) {
        for (int bb = 0; bb < BT; ++bb)
            sPart1[((size_t)ic * B_ + (b0 + bb)) * CO_ + tid] = sred[bb][tid];
    }
}

// ---------------------------------------------------------------------------
// route_all: one block per b; 640 thr = (il 0..63, c 0..9).
// veff1 -> round2 -> (reduce+squash) -> veff2 -> round3 -> out.
// One barrier per batch (pb double-buffered); next-batch hat regs prefetched.
// All reductions in fixed order -> deterministic.
// ---------------------------------------------------------------------------
__global__ __launch_bounds__(TRA) void k_route_all(
    const __hip_bfloat16* __restrict__ hat,  // [B,I,CO]
    const float* __restrict__ sPart1,        // [NIC1][B][CO]
    float* __restrict__ out)                 // [B,CO]
{
    __shared__ float pb[2][64][C_];       // 5 KB
    __shared__ float sr[64][CO_ + 4];     // 42 KB (+4 pad: bank spread)
    __shared__ float red4[4][CO_];        // 2.5 KB
    __shared__ float veffs[CO_];
    const int tid = threadIdx.x;
    const int il = tid / C_, c = tid % C_;
    const int b = blockIdx.x;
    const int q = tid / CO_;              // 0..3
    const int co = tid % CO_;

    // ---- veff1 = squash((sum_k sPart1[k][b]) / C), 4-way split ----
    {
        float s = 0.0f;
        #pragma unroll 2
        for (int j = 0; j < NIC1 / 4; ++j)
            s += sPart1[((size_t)(q * (NIC1 / 4) + j) * B_ + b) * CO_ + co];
        red4[q][co] = s;
    }
    __syncthreads();
    if (tid < CO_) {
        float s = ((red4[0][tid] + red4[1][tid]) + (red4[2][tid] + red4[3][tid]))
                  * (1.0f / C_);
        float n2 = s * s;
        n2 += __shfl_xor(n2, 1);
        n2 += __shfl_xor(n2, 2);
        n2 += __shfl_xor(n2, 4);
        n2 += __shfl_xor(n2, 8);
        const float sc = n2 / ((1.0f + n2) * sqrtf(n2 + EPS_));
        veffs[tid] = s * sc;
    }
    __syncthreads();

    const size_t baseB = (size_t)b * I_;

    for (int round = 0; round < 2; ++round) {
        float vr[O_];
        #pragma unroll
        for (int o = 0; o < O_; ++o) vr[o] = veffs[c * O_ + o];
        float sacc[O_];
        #pragma unroll
        for (int o = 0; o < O_; ++o) sacc[o] = 0.0f;

        uint4 ha, hb2, han, hbn;
        {
            const uint4* p0 = (const uint4*)&hat[(baseB + il) * CO_ + c * O_];
            ha = p0[0]; hb2 = p0[1];
        }
        for (int batch = 0; batch < NBATCH; ++batch) {
            if (batch < NBATCH - 1) {   // prefetch next batch's hat row
                const uint4* pn = (const uint4*)
                    &hat[(baseB + (batch + 1) * 64 + il) * CO_ + c * O_];
                han = pn[0]; hbn = pn[1];
            }
            float hf[O_];
            {
                const unsigned u[8] = {ha.x, ha.y, ha.z, ha.w,
                                       hb2.x, hb2.y, hb2.z, hb2.w};
                #pragma unroll
                for (int t = 0; t < 8; ++t) {
                    hf[2 * t]     = __uint_as_float(u[t] << 16);
                    hf[2 * t + 1] = __uint_as_float(u[t] & 0xffff0000u);
                }
            }
            float p = 0.0f;
            #pragma unroll
            for (int o = 0; o < O_; ++o) p = fmaf(hf[o], vr[o], p);
            pb[batch & 1][il][c] = p;
            __syncthreads();
            // local softmax over the 10 logits (same order in all threads)
            float pv[C_];
            #pragma unroll
            for (int qq = 0; qq < C_; ++qq) pv[qq] = pb[batch & 1][il][qq];
            float m = pv[0];
            #pragma unroll
            for (int qq = 1; qq < C_; ++qq) m = fmaxf(m, pv[qq]);
            float sum = 0.0f;
            #pragma unroll
            for (int qq = 0; qq < C_; ++qq) sum += __expf(pv[qq] - m);
            const float route = __expf(p - m) * __builtin_amdgcn_rcpf(sum);
            #pragma unroll
            for (int o = 0; o < O_; ++o) sacc[o] = fmaf(route, hf[o], sacc[o]);
            ha = han; hb2 = hbn;
            // no second barrier: pb is double-buffered; the write to this
            // buffer 2 batches later is ordered by the next batch's barrier.
        }

        // ---- reduce sacc over the 64 il groups (fixed order) ----
        #pragma unroll
        for (int o = 0; o < O_; ++o) sr[il][c * O_ + o] = sacc[o];
        __syncthreads();
        {
            float s = 0.0f;
            #pragma unroll
            for (int j = 0; j < 16; ++j) s += sr[q * 16 + j][co];
            red4[q][co] = s;
        }
        __syncthreads();
        if (tid < CO_) {
            float s = (red4[0][tid] + red4[1][tid]) + (red4[2][tid] + red4[3][tid]);
            float n2 = s * s;
            n2 += __shfl_xor(n2, 1);
            n2 += __shfl_xor(n2, 2);
            n2 += __shfl_xor(n2, 4);
            n2 += __shfl_xor(n2, 8);
            const float sc = n2 / ((1.0f + n2) * sqrtf(n2 + EPS_));
            const float v = s * sc;
            if (round == 0) veffs[tid] += v;           // veff2 = veff1 + v1
            else out[(size_t)b * CO_ + tid] = v;       // final output
        }
        __syncthreads();
    }
}

// ---------------------------------------------------------------------------
// Fallback: fully fused single kernel (~402 us) if ws too small
// ---------------------------------------------------------------------------
#define THREADS 640
#define ILG 8
#define SUBI 4
#define CHUNK (ILG*SUBI)
#define NITER (I_/CHUNK)

__global__ __launch_bounds__(THREADS) void capsule_routing_kernel(
    const float* __restrict__ x, const float* __restrict__ W,
    float* __restrict__ out)
{
    __shared__ float bias[I_ * C_];
    __shared__ float spart[ILG][C_ * O_];
    __shared__ float sv[C_ * O_];
    __shared__ float vv[C_ * O_];
    __shared__ float ech[CHUNK][C_];
    __shared__ float scale[C_];

    const int b   = blockIdx.x;
    const int tid = threadIdx.x;
    for (int j = tid; j < I_ * C_; j += THREADS) bias[j] = 0.0f;
    const int il = tid / 80;
    const int rr = tid % 80;
    const int c  = rr / 8;
    const int o2 = rr % 8;
    const int o0 = o2 * 2;
    const float* xb = x + (size_t)b * I_ * D_;
    const float2* W2 = (const float2*)W;
    __syncthreads();
    {
        float acc0 = 0.0f, acc1 = 0.0f;
        for (int it = 0; it < NITER; ++it) {
            #pragma unroll
            for (int sub = 0; sub < SUBI; ++sub) {
                const int i = it * CHUNK + sub * ILG + il;
                const float* xi = xb + i * D_;
                const float2* wp = W2 + (i * C_ + c) * (D_ * O_ / 2) + o2;
                float h0 = 0.0f, h1 = 0.0f;
                #pragma unroll
                for (int d = 0; d < D_; ++d) {
                    float2 w = wp[d * (O_ / 2)];
                    float xv = xi[d];
                    h0 = fmaf(xv, w.x, h0);
                    h1 = fmaf(xv, w.y, h1);
                }
                acc0 += h0; acc1 += h1;
            }
        }
        spart[il][c * O_ + o0]     = acc0;
        spart[il][c * O_ + o0 + 1] = acc1;
    }
    __syncthreads();
    if (tid < C_ * O_) {
        float s = 0.0f;
        #pragma unroll
        for (int k = 0; k < ILG; ++k) s += spart[k][tid];
        sv[tid] = s * (1.0f / C_);
    }
    __syncthreads();
    if (tid < C_) {
        float n2 = 0.0f;
        #pragma unroll
        for (int o = 0; o < O_; ++o) { float t = sv[tid * O_ + o]; n2 = fmaf(t, t, n2); }
        scale[tid] = n2 / ((1.0f + n2) * sqrtf(n2 + EPS_));
    }
    __syncthreads();
    if (tid < C_ * O_) vv[tid] = sv[tid] * scale[tid / O_];
    __syncthreads();
    for (int pass = 1; pass < 3; ++pass) {
        float sa0 = 0.0f, sa1 = 0.0f;
        for (int it = 0; it < NITER; ++it) {
            float h0s[SUBI], h1s[SUBI];
            const float v0 = vv[c * O_ + o0];
            const float v1 = vv[c * O_ + o0 + 1];
            #pragma unroll
            for (int sub = 0; sub < SUBI; ++sub) {
                const int i = it * CHUNK + sub * ILG + il;
                const float* xi = xb + i * D_;
                const float2* wp = W2 + (i * C_ + c) * (D_ * O_ / 2) + o2;
                float h0 = 0.0f, h1 = 0.0f;
                #pragma unroll
                for (int d = 0; d < D_; ++d) {
                    float2 w = wp[d * (O_ / 2)];
                    float xv = xi[d];
                    h0 = fmaf(xv, w.x, h0);
                    h1 = fmaf(xv, w.y, h1);
                }
                h0s[sub] = h0; h1s[sub] = h1;
                float p = h0 * v0 + h1 * v1;
                p += __shfl_xor(p, 1);
                p += __shfl_xor(p, 2);
                p += __shfl_xor(p, 4);
                if (o2 == 0) bias[i * C_ + c] += p;
            }
            __syncthreads();
            if (tid < CHUNK * C_) {
                const int il2 = tid / C_, cc = tid % C_;
                const int i = it * CHUNK + il2;
                float m = -1e30f;
                #pragma unroll
                for (int k = 0; k < C_; ++k) m = fmaxf(m, bias[i * C_ + k]);
                ech[il2][cc] = __expf(bias[i * C_ + cc] - m);
            }
            __syncthreads();
            #pragma unroll
            for (int sub = 0; sub < SUBI; ++sub) {
                const int icx = sub * ILG + il;
                float sum = 0.0f;
                #pragma unroll
                for (int k = 0; k < C_; ++k) sum += ech[icx][k];
                const float route = ech[icx][c] / sum;
                sa0 = fmaf(route, h0s[sub], sa0);
                sa1 = fmaf(route, h1s[sub], sa1);
            }
            __syncthreads();
        }
        spart[il][c * O_ + o0]     = sa0;
        spart[il][c * O_ + o0 + 1] = sa1;
        __syncthreads();
        if (tid < C_ * O_) {
            float s = 0.0f;
            #pragma unroll
            for (int k = 0; k < ILG; ++k) s += spart[k][tid];
            sv[tid] = s;
        }
        __syncthreads();
        if (tid < C_) {
            float n2 = 0.0f;
            #pragma unroll
            for (int o = 0; o < O_; ++o) { float t = sv[tid * O_ + o]; n2 = fmaf(t, t, n2); }
            scale[tid] = n2 / ((1.0f + n2) * sqrtf(n2 + EPS_));
        }
        __syncthreads();
        if (tid < C_ * O_) vv[tid] = sv[tid] * scale[tid / O_];
        __syncthreads();
    }
    if (tid < C_ * O_) out[(size_t)b * C_ * O_ + tid] = vv[tid];
}

// ---------------------------------------------------------------------------
extern "C" void kernel_launch(void* const* d_in, const int* in_sizes, int n_in,
                              void* d_out, int out_size, void* d_ws, size_t ws_size,
                              hipStream_t stream) {
    (void)in_sizes; (void)n_in; (void)out_size;
    const float* x = (const float*)d_in[0];
    const float* W = (const float*)d_in[1];
    float* out = (float*)d_out;

    const size_t hat_b  = (size_t)B_ * I_ * CO_ * sizeof(__hip_bfloat16); // 94.4 MB
    const size_t sp1_b  = (size_t)NIC1 * B_ * CO_ * sizeof(float);        // 11.8 MB
    const size_t need   = hat_b + sp1_b;                                  // ~106 MB

    if (ws_size >= need) {
        char* p = (char*)d_ws;
        __hip_bfloat16* hat = (__hip_bfloat16*)p;  p += hat_b;
        float* sPart1 = (float*)p;

        k1_hat<<<dim3(NIC1, NBT), T1, 0, stream>>>(x, W, hat, sPart1);
        k_route_all<<<B_, TRA, 0, stream>>>(hat, sPart1, out);
    } else {
        capsule_routing_kernel<<<B_, THREADS, 0, stream>>>(x, W, out);
    }
}